// Round 1
// baseline (2284.826 us; speedup 1.0000x reference)
//
#include <hip/hip_runtime.h>
#include <math.h>

// ---------------- problem constants ----------------
// B=2, S=240, WIDTH=128, M=20, PAD=16 -> padded spatial 256x256
// modes: kx in {0..19} (w1) and {236..255} (w2) -> j=0..39 ; ky in {0..19}

// ---------------- ws layout (float offsets) ----------------
#define SZ_H   (2ull*256*256*128)          // 8,388,608 floats
#define O_HA   0ull
#define O_HB   (O_HA + SZ_H)
#define O_G    (O_HB + SZ_H)               // float2[2*256*20*128]
#define SZ_G   (2ull*256*20*128*2)
#define O_FTT  (O_G + SZ_G)                // float2[128*2*800]
#define SZ_FT  (2ull*40*20*128*2)
#define O_OFT  (O_FTT + SZ_FT)
#define O_EY   (O_OFT + SZ_FT)             // float2[256*20]
#define SZ_EY  (256ull*20*2)
#define O_EX   (O_EY + SZ_EY)              // float2[256*40]
#define SZ_EX  (256ull*40*2)
#define O_EXI  (O_EX + SZ_EX)
#define O_WWT  (O_EXI + SZ_EX)             // 5*128*128 transposed w_w
// total = 20,350,976 floats = ~81.4 MB

static __device__ __forceinline__ float gelu_f(float v) {
    return 0.5f * v * (1.0f + erff(v * 0.70710678118654752f));
}

// ---------------- K0: tables + w_w transpose ----------------
__global__ void k_prep(const float* __restrict__ w_w, float* __restrict__ ws) {
    int i = blockIdx.x * 256 + threadIdx.x;
    const float STEP = 6.2831853071795864769f / 256.0f;
    if (i < 5120) {                       // Ey[y][ky] = exp(-2pi i ky y/256)
        int ky = i % 20, y = i / 20;
        int t = (ky * y) & 255;
        float th = t * STEP;
        ws[O_EY + 2*(size_t)i]     = cosf(th);
        ws[O_EY + 2*(size_t)i + 1] = -sinf(th);
    } else if (i < 15360) {               // Ex[x][j] = exp(-2pi i kx x/256)
        int m = i - 5120; int j = m % 40, x = m / 40;
        int kx = (j < 20) ? j : (216 + j);
        int t = (kx * x) & 255;
        float th = t * STEP;
        ws[O_EX + 2*(size_t)m]     = cosf(th);
        ws[O_EX + 2*(size_t)m + 1] = -sinf(th);
    } else if (i < 25600) {               // Exi[x][j] = exp(+2pi i kx x/256)
        int m = i - 15360; int j = m % 40, x = m / 40;
        int kx = (j < 20) ? j : (216 + j);
        int t = (kx * x) & 255;
        float th = t * STEP;
        ws[O_EXI + 2*(size_t)m]     = cosf(th);
        ws[O_EXI + 2*(size_t)m + 1] = sinf(th);
    } else {                              // wwT[l][ic][oc] = w_w[l][oc][ic]
        int m = i - 25600;
        if (m < 81920) {
            int l = m >> 14, r = m & 16383;
            int ic = r >> 7, oc = r & 127;
            ws[O_WWT + m] = w_w[(size_t)l*16384 + oc*128 + ic];
        }
    }
}

// ---------------- K1: fc0 + grid concat + zero-pad ----------------
__global__ void k_fc0(const float* __restrict__ xin, const float* __restrict__ w,
                      const float* __restrict__ bv, float* __restrict__ H) {
    size_t e = (size_t)blockIdx.x * 256 + threadIdx.x;   // < 16,777,216
    int c = (int)(e & 127);
    int y = (int)((e >> 7) & 255);
    int x = (int)((e >> 15) & 255);
    int b = (int)(e >> 23);
    float h = 0.0f;
    if (x < 240 && y < 240) {
        const float* xp = xin + (((size_t)(b*240 + x))*240 + y)*3;
        h = bv[c] + xp[0]*w[c] + xp[1]*w[128+c] + xp[2]*w[256+c]
          + (x*(1.0f/239.0f))*w[384+c] + (y*(1.0f/239.0f))*w[512+c];
    }
    H[e] = h;
}

// ---------------- K2: y-DFT  H -> G[b][x][ky][c] ----------------
__global__ __launch_bounds__(256) void k_ydft(const float* __restrict__ H,
        const float* __restrict__ Ey, float2* __restrict__ G) {
    int b = blockIdx.x >> 8, x = blockIdx.x & 255;
    int c = threadIdx.x & 127;
    int yq = __builtin_amdgcn_readfirstlane((int)(threadIdx.x >> 7));  // 0,1
    const float* Hrow = H + ((size_t)(b*256 + x)) * 256 * 128;
    float ar[20], ai[20];
    #pragma unroll
    for (int k = 0; k < 20; k++) { ar[k] = 0.f; ai[k] = 0.f; }
    for (int i = 0; i < 128; i++) {
        int y = yq*128 + i;
        float v = Hrow[(size_t)y*128 + c];
        const float* e = Ey + (size_t)y*40;
        #pragma unroll
        for (int k = 0; k < 20; k++) {
            ar[k] = fmaf(v, e[2*k],   ar[k]);
            ai[k] = fmaf(v, e[2*k+1], ai[k]);
        }
    }
    __shared__ float red[20][128][2];   // 20 KB
    if (yq == 1) {
        #pragma unroll
        for (int k = 0; k < 20; k++) { red[k][c][0] = ar[k]; red[k][c][1] = ai[k]; }
    }
    __syncthreads();
    if (yq == 0) {
        float2* Gp = G + ((size_t)(b*256 + x))*20*128;
        #pragma unroll
        for (int k = 0; k < 20; k++)
            Gp[k*128 + c] = make_float2(ar[k] + red[k][c][0], ai[k] + red[k][c][1]);
    }
}

// ---------------- K3: x-DFT  G -> ftT[ic][b][j*20+ky] ----------------
__global__ __launch_bounds__(512) void k_xdft(const float2* __restrict__ G,
        const float* __restrict__ Ex, float2* __restrict__ ftT) {
    // grid: b(2)*ky(20)*jq(2) = 80 ; block 512 = xq(4) x c(128)
    int jq = blockIdx.x & 1;
    int ky = (blockIdx.x >> 1) % 20;
    int b  = blockIdx.x / 40;
    int c  = threadIdx.x & 127;
    int xq = __builtin_amdgcn_readfirstlane((int)(threadIdx.x >> 7));  // 0..3
    int j0 = jq * 20;
    float ar[20], ai[20];
    #pragma unroll
    for (int k = 0; k < 20; k++) { ar[k] = 0.f; ai[k] = 0.f; }
    for (int i = 0; i < 64; i++) {
        int x = xq*64 + i;
        float2 g = G[(((size_t)(b*256 + x))*20 + ky)*128 + c];
        const float* e = Ex + (size_t)x*80 + j0*2;
        #pragma unroll
        for (int k = 0; k < 20; k++) {
            float er = e[2*k], ei = e[2*k+1];
            ar[k] = fmaf(g.x, er, fmaf(-g.y, ei, ar[k]));
            ai[k] = fmaf(g.x, ei, fmaf( g.y, er, ai[k]));
        }
    }
    __shared__ float red[2][20][128][2];  // 40 KB
    if (xq >= 2) {
        int s = xq - 2;
        #pragma unroll
        for (int k = 0; k < 20; k++) { red[s][k][c][0] = ar[k]; red[s][k][c][1] = ai[k]; }
    }
    __syncthreads();
    if (xq < 2) {
        #pragma unroll
        for (int k = 0; k < 20; k++) { ar[k] += red[xq][k][c][0]; ai[k] += red[xq][k][c][1]; }
    }
    __syncthreads();
    if (xq == 1) {
        #pragma unroll
        for (int k = 0; k < 20; k++) { red[0][k][c][0] = ar[k]; red[0][k][c][1] = ai[k]; }
    }
    __syncthreads();
    if (xq == 0) {
        #pragma unroll
        for (int k = 0; k < 20; k++) {
            float rr = ar[k] + red[0][k][c][0];
            float ii = ai[k] + red[0][k][c][1];
            ftT[((size_t)c*2 + b)*800 + (size_t)(j0 + k)*20 + ky] = make_float2(rr, ii);
        }
    }
}

// ---------------- K4: mode mixing (the HBM-heavy einsum) ----------------
__global__ __launch_bounds__(448) void k_modemix(const float2* __restrict__ w1,
        const float2* __restrict__ w2, const float2* __restrict__ ftT,
        float2* __restrict__ oft) {
    // grid 256 = oc(128) x mh(2) ; lanes sweep contiguous (mx,my)
    int oc = blockIdx.x >> 1;
    int mh = blockIdx.x & 1;
    int tid = threadIdx.x;
    if (tid >= 400) return;
    int wsel = tid / 200;
    int m = mh*200 + (tid % 200);          // 0..399 within w1 or w2
    int jk = wsel*400 + m;                  // flat (j*20+ky)
    const float2* wb = wsel ? w2 : w1;
    float ar0=0.f, ai0=0.f, ar1=0.f, ai1=0.f;
    for (int ic = 0; ic < 128; ic++) {
        float2 wv = wb[((size_t)(ic*128 + oc))*400 + m];
        float2 f0 = ftT[(size_t)ic*1600 + jk];
        float2 f1 = ftT[(size_t)ic*1600 + 800 + jk];
        ar0 = fmaf(f0.x, wv.x, fmaf(-f0.y, wv.y, ar0));
        ai0 = fmaf(f0.x, wv.y, fmaf( f0.y, wv.x, ai0));
        ar1 = fmaf(f1.x, wv.x, fmaf(-f1.y, wv.y, ar1));
        ai1 = fmaf(f1.x, wv.y, fmaf( f1.y, wv.x, ai1));
    }
    oft[(size_t)jk*128 + oc]         = make_float2(ar0, ai0);
    oft[(size_t)(800 + jk)*128 + oc] = make_float2(ar1, ai1);
}

// ---------------- K5: x-IDFT  oft -> T[b][x][ky][oc] (into G buffer) ---
__global__ __launch_bounds__(512) void k_xidft(const float2* __restrict__ oft,
        const float* __restrict__ Exi, float2* __restrict__ T) {
    // grid: b(2)*xq(64) ; block 512 = xs(4) x oc(128)
    int b = blockIdx.x >> 6, xq = blockIdx.x & 63;
    int oc = threadIdx.x & 127;
    int xs = __builtin_amdgcn_readfirstlane((int)(threadIdx.x >> 7));
    int x = xq*4 + xs;
    float ar[20], ai[20];
    #pragma unroll
    for (int k = 0; k < 20; k++) { ar[k] = 0.f; ai[k] = 0.f; }
    const float2* ob = oft + (size_t)b*800*128;
    for (int j = 0; j < 40; j++) {
        float er = Exi[(size_t)x*80 + 2*j], ei = Exi[(size_t)x*80 + 2*j + 1];
        #pragma unroll
        for (int k = 0; k < 20; k++) {
            float2 o = ob[(size_t)(j*20 + k)*128 + oc];
            ar[k] = fmaf(o.x, er, fmaf(-o.y, ei, ar[k]));
            ai[k] = fmaf(o.x, ei, fmaf( o.y, er, ai[k]));
        }
    }
    float2* Tp = T + ((size_t)(b*256 + x))*20*128;
    #pragma unroll
    for (int k = 0; k < 20; k++) Tp[k*128 + oc] = make_float2(ar[k], ai[k]);
}

// ---------------- K6: y-IDFT + pointwise linear + bias + gelu ----------
__global__ __launch_bounds__(128) void k_spec_lin(const float* __restrict__ H,
        const float2* __restrict__ T, const float* __restrict__ wwT,
        const float* __restrict__ wb, float* __restrict__ Hout, int do_gelu) {
    // grid: ((b*256)+x)*8 + yg ; block 128 = ocg(32) x ys(4); tile 4oc x 8y
    int yg = blockIdx.x & 7;
    int x  = (blockIdx.x >> 3) & 255;
    int b  = blockIdx.x >> 11;
    int tid = threadIdx.x;
    int ocg = tid & 31;
    int ys  = tid >> 5;
    __shared__ float  Hl[32][128];     // 16 KB
    __shared__ float2 Tl[20][128];     // 20 KB
    __shared__ float2 trig[20][32];    // 5 KB
    const float* Hbase = H + (((size_t)(b*256 + x))*256 + yg*32)*128;
    for (int yy = 0; yy < 32; yy++) Hl[yy][tid] = Hbase[(size_t)yy*128 + tid];
    const float2* Tp = T + ((size_t)(b*256 + x))*20*128;
    for (int i = tid; i < 2560; i += 128) Tl[i>>7][i&127] = Tp[i];
    int y0 = yg*32;
    for (int i = tid; i < 640; i += 128) {
        int ky = i >> 5, yl = i & 31;
        int t = (ky * (y0 + yl)) & 255;
        float th = t * (6.2831853071795864769f/256.0f);
        float f = (ky == 0 ? 1.0f : 2.0f) * (1.0f/65536.0f);
        trig[ky][yl] = make_float2(f*cosf(th), f*sinf(th));
    }
    __syncthreads();
    int oc0 = ocg*4;
    float acc[4][8];
    #pragma unroll
    for (int q = 0; q < 4; q++)
        #pragma unroll
        for (int yy = 0; yy < 8; yy++) acc[q][yy] = 0.f;
    // pointwise linear: acc += W^T h
    #pragma unroll 4
    for (int ic = 0; ic < 128; ic++) {
        float4 w = *reinterpret_cast<const float4*>(wwT + (size_t)ic*128 + oc0);
        #pragma unroll
        for (int yy = 0; yy < 8; yy++) {
            float h = Hl[ys*8+yy][ic];
            acc[0][yy] = fmaf(h, w.x, acc[0][yy]);
            acc[1][yy] = fmaf(h, w.y, acc[1][yy]);
            acc[2][yy] = fmaf(h, w.z, acc[2][yy]);
            acc[3][yy] = fmaf(h, w.w, acc[3][yy]);
        }
    }
    // spectral part: acc += f(ky)/65536 * (Tr cos - Ti sin)
    #pragma unroll
    for (int ky = 0; ky < 20; ky++) {
        float2 t0 = Tl[ky][oc0+0], t1 = Tl[ky][oc0+1];
        float2 t2 = Tl[ky][oc0+2], t3 = Tl[ky][oc0+3];
        #pragma unroll
        for (int yy = 0; yy < 8; yy++) {
            float2 cs = trig[ky][ys*8+yy];
            acc[0][yy] = fmaf(t0.x, cs.x, fmaf(-t0.y, cs.y, acc[0][yy]));
            acc[1][yy] = fmaf(t1.x, cs.x, fmaf(-t1.y, cs.y, acc[1][yy]));
            acc[2][yy] = fmaf(t2.x, cs.x, fmaf(-t2.y, cs.y, acc[2][yy]));
            acc[3][yy] = fmaf(t3.x, cs.x, fmaf(-t3.y, cs.y, acc[3][yy]));
        }
    }
    float b0 = wb[oc0], b1 = wb[oc0+1], b2 = wb[oc0+2], b3 = wb[oc0+3];
    #pragma unroll
    for (int yy = 0; yy < 8; yy++) {
        float4 o;
        o.x = acc[0][yy] + b0; o.y = acc[1][yy] + b1;
        o.z = acc[2][yy] + b2; o.w = acc[3][yy] + b3;
        if (do_gelu) { o.x = gelu_f(o.x); o.y = gelu_f(o.y); o.z = gelu_f(o.z); o.w = gelu_f(o.w); }
        *reinterpret_cast<float4*>(Hout + (((size_t)(b*256 + x))*256 + y0 + ys*8 + yy)*128 + oc0) = o;
    }
}

// ---------------- K7: crop + fc1 + gelu + heads (fused via LDS) --------
__global__ __launch_bounds__(256) void k_head(const float* __restrict__ H,
        const float* __restrict__ fc1_w, const float* __restrict__ fc1_b,
        const float* __restrict__ h1w, const float* __restrict__ h1b,
        const float* __restrict__ h2w, const float* __restrict__ h2b,
        float* __restrict__ out) {
    int tid = threadIdx.x;
    int p0 = blockIdx.x * 32;              // 3600 blocks, 115200 pixels
    __shared__ float hl[32][128];          // 16 KB
    __shared__ float tl[128][36];          // 18 KB, pitch 36 for b128 reads
    for (int i = tid; i < 4096; i += 256) {
        int pi = i >> 7, c = i & 127;
        int p = p0 + pi;
        int b = p / 57600, r = p % 57600;
        int xx = r / 240, yy = r % 240;
        hl[pi][c] = H[(((size_t)(b*256 + xx))*256 + yy)*128 + c];
    }
    __syncthreads();
    {   // fc1: thread (oc, ps) -> 16 pixels
        int oc = tid & 127, ps = tid >> 7;
        float acc[16];
        #pragma unroll
        for (int pi = 0; pi < 16; pi++) acc[pi] = 0.f;
        for (int ic = 0; ic < 128; ic++) {
            float w = fc1_w[(size_t)ic*128 + oc];
            #pragma unroll
            for (int pi = 0; pi < 16; pi++)
                acc[pi] = fmaf(hl[ps*16+pi][ic], w, acc[pi]);
        }
        float bb = fc1_b[oc];
        #pragma unroll
        for (int pi = 0; pi < 16; pi++)
            tl[oc][ps*16+pi] = gelu_f(acc[pi] + bb);
    }
    __syncthreads();
    // heads: thread (k = wave, d = lane); reduce over d via shuffles
    int k = tid >> 6, d = tid & 63;
    float accp[32];
    #pragma unroll
    for (int pi = 0; pi < 32; pi++) accp[pi] = 0.f;
    const float* w1p = h1w + (size_t)k*8192 + d;
    for (int c = 0; c < 128; c++) {
        float w = w1p[(size_t)c*64];
        #pragma unroll
        for (int pi = 0; pi < 32; pi++)
            accp[pi] = fmaf(tl[c][pi], w, accp[pi]);
    }
    float b1 = h1b[k*64 + d];
    float w2 = h2w[k*64 + d];
    float ob = h2b[k];
    for (int pi = 0; pi < 32; pi++) {
        float u = gelu_f(accp[pi] + b1) * w2;
        u += __shfl_down(u, 32);
        u += __shfl_down(u, 16);
        u += __shfl_down(u, 8);
        u += __shfl_down(u, 4);
        u += __shfl_down(u, 2);
        u += __shfl_down(u, 1);
        if (d == 0) out[(size_t)k*115200 + p0 + pi] = u + ob;
    }
}

// ---------------- launcher ----------------
extern "C" void kernel_launch(void* const* d_in, const int* in_sizes, int n_in,
                              void* d_out, int out_size, void* d_ws, size_t ws_size,
                              hipStream_t stream) {
    const float* x       = (const float*)d_in[0];
    const float* fc0_w   = (const float*)d_in[1];
    const float* fc0_b   = (const float*)d_in[2];
    const float* spec_w1 = (const float*)d_in[3];
    const float* spec_w2 = (const float*)d_in[4];
    const float* w_w     = (const float*)d_in[5];
    const float* w_b     = (const float*)d_in[6];
    const float* fc1_w   = (const float*)d_in[7];
    const float* fc1_b   = (const float*)d_in[8];
    const float* head1_w = (const float*)d_in[9];
    const float* head1_b = (const float*)d_in[10];
    const float* head2_w = (const float*)d_in[11];
    const float* head2_b = (const float*)d_in[12];
    float* ws = (float*)d_ws;
    float* out = (float*)d_out;

    k_prep<<<420, 256, 0, stream>>>(w_w, ws);
    k_fc0<<<65536, 256, 0, stream>>>(x, fc0_w, fc0_b, ws + O_HA);

    float* cur = ws + O_HA;
    float* nxt = ws + O_HB;
    float2* G   = (float2*)(ws + O_G);
    float2* ftT = (float2*)(ws + O_FTT);
    float2* oft = (float2*)(ws + O_OFT);

    for (int l = 0; l < 5; l++) {
        k_ydft<<<512, 256, 0, stream>>>(cur, ws + O_EY, G);
        k_xdft<<<80, 512, 0, stream>>>(G, ws + O_EX, ftT);
        k_modemix<<<256, 448, 0, stream>>>(
            (const float2*)(spec_w1 + (size_t)l*13107200),
            (const float2*)(spec_w2 + (size_t)l*13107200), ftT, oft);
        k_xidft<<<128, 512, 0, stream>>>(oft, ws + O_EXI, G);   // T into G
        k_spec_lin<<<4096, 128, 0, stream>>>(cur, G, ws + O_WWT + (size_t)l*16384,
                                             w_b + l*128, nxt, (l < 4) ? 1 : 0);
        float* t = cur; cur = nxt; nxt = t;
    }
    k_head<<<3600, 256, 0, stream>>>(cur, fc1_w, fc1_b, head1_w, head1_b,
                                     head2_w, head2_b, out);
}

// Round 2
// 2087.794 us; speedup vs baseline: 1.0944x; 1.0944x over previous
//
#include <hip/hip_runtime.h>
#include <math.h>

// ---------------- problem constants ----------------
// B=2, S=240, WIDTH=128, M=20, PAD=16 -> padded spatial 256x256
// modes: kx in {0..19} (w1) and {236..255} (w2) -> j=0..39 ; ky in {0..19}

// ---------------- ws layout (float offsets) ----------------
#define SZ_H   (2ull*256*256*128)          // 8,388,608 floats
#define O_HA   0ull
#define O_HB   (O_HA + SZ_H)
#define O_G    (O_HB + SZ_H)               // float2[2*256*20*128]
#define SZ_G   (2ull*256*20*128*2)
#define O_FTT  (O_G + SZ_G)                // float2[128*2*800]
#define SZ_FT  (2ull*40*20*128*2)
#define O_OFT  (O_FTT + SZ_FT)
#define O_EY   (O_OFT + SZ_FT)             // float2[256*20]
#define SZ_EY  (256ull*20*2)
#define O_EX   (O_EY + SZ_EY)              // float2[256*40]
#define SZ_EX  (256ull*40*2)
#define O_EXI  (O_EX + SZ_EX)
#define O_WWT  (O_EXI + SZ_EX)             // 5*128*128 transposed w_w
#define SZ_WWT 81920ull
#define O_PART (O_WWT + SZ_WWT)            // 8 x 204800 float2 partials
#define SZ_PART (8ull*204800*2)

static __device__ __forceinline__ float gelu_f(float v) {
    return 0.5f * v * (1.0f + erff(v * 0.70710678118654752f));
}

// ---------------- K0: tables + w_w transpose ----------------
__global__ void k_prep(const float* __restrict__ w_w, float* __restrict__ ws) {
    int i = blockIdx.x * 256 + threadIdx.x;
    const float STEP = 6.2831853071795864769f / 256.0f;
    if (i < 5120) {                       // Ey[y][ky] = exp(-2pi i ky y/256)
        int ky = i % 20, y = i / 20;
        int t = (ky * y) & 255;
        float th = t * STEP;
        ws[O_EY + 2*(size_t)i]     = cosf(th);
        ws[O_EY + 2*(size_t)i + 1] = -sinf(th);
    } else if (i < 15360) {               // Ex[x][j] = exp(-2pi i kx x/256)
        int m = i - 5120; int j = m % 40, x = m / 40;
        int kx = (j < 20) ? j : (216 + j);
        int t = (kx * x) & 255;
        float th = t * STEP;
        ws[O_EX + 2*(size_t)m]     = cosf(th);
        ws[O_EX + 2*(size_t)m + 1] = -sinf(th);
    } else if (i < 25600) {               // Exi[x][j] = exp(+2pi i kx x/256)
        int m = i - 15360; int j = m % 40, x = m / 40;
        int kx = (j < 20) ? j : (216 + j);
        int t = (kx * x) & 255;
        float th = t * STEP;
        ws[O_EXI + 2*(size_t)m]     = cosf(th);
        ws[O_EXI + 2*(size_t)m + 1] = sinf(th);
    } else {                              // wwT[l][ic][oc] = w_w[l][oc][ic]
        int m = i - 25600;
        if (m < 81920) {
            int l = m >> 14, r = m & 16383;
            int ic = r >> 7, oc = r & 127;
            ws[O_WWT + m] = w_w[(size_t)l*16384 + oc*128 + ic];
        }
    }
}

// ---------------- K1: fc0 + grid concat + zero-pad (float4) -----------
__global__ __launch_bounds__(256) void k_fc0(const float* __restrict__ xin,
        const float* __restrict__ w, const float* __restrict__ bv,
        float4* __restrict__ H4) {
    size_t e = (size_t)blockIdx.x * 256 + threadIdx.x;   // < 4,194,304
    int c4 = (int)(e & 31) * 4;
    int y = (int)((e >> 5) & 255);
    int x = (int)((e >> 13) & 255);
    int b = (int)(e >> 21);
    float4 h = make_float4(0.f, 0.f, 0.f, 0.f);
    if (x < 240 && y < 240) {
        const float* xp = xin + (((size_t)(b*240 + x))*240 + y)*3;
        float x0 = xp[0], x1 = xp[1], x2 = xp[2];
        float gx = x*(1.0f/239.0f), gy = y*(1.0f/239.0f);
        float4 w0 = *(const float4*)&w[c4];
        float4 w1 = *(const float4*)&w[128 + c4];
        float4 w2 = *(const float4*)&w[256 + c4];
        float4 w3 = *(const float4*)&w[384 + c4];
        float4 w4 = *(const float4*)&w[512 + c4];
        float4 bb = *(const float4*)&bv[c4];
        h.x = bb.x + x0*w0.x + x1*w1.x + x2*w2.x + gx*w3.x + gy*w4.x;
        h.y = bb.y + x0*w0.y + x1*w1.y + x2*w2.y + gx*w3.y + gy*w4.y;
        h.z = bb.z + x0*w0.z + x1*w1.z + x2*w2.z + gx*w3.z + gy*w4.z;
        h.w = bb.w + x0*w0.w + x1*w1.w + x2*w2.w + gx*w3.w + gy*w4.w;
    }
    H4[e] = h;
}

// ---------------- K2: y-DFT  H -> G[b][x][ky][c] ----------------
__global__ __launch_bounds__(256) void k_ydft(const float* __restrict__ H,
        const float* __restrict__ Ey, float2* __restrict__ G) {
    int b = blockIdx.x >> 8, x = blockIdx.x & 255;
    int c = threadIdx.x & 127;
    int yq = __builtin_amdgcn_readfirstlane((int)(threadIdx.x >> 7));  // 0,1
    const float* Hrow = H + ((size_t)(b*256 + x)) * 256 * 128;
    float ar[20], ai[20];
    #pragma unroll
    for (int k = 0; k < 20; k++) { ar[k] = 0.f; ai[k] = 0.f; }
    for (int i = 0; i < 128; i++) {
        int y = yq*128 + i;
        float v = Hrow[(size_t)y*128 + c];
        const float* e = Ey + (size_t)y*40;
        #pragma unroll
        for (int k = 0; k < 20; k++) {
            ar[k] = fmaf(v, e[2*k],   ar[k]);
            ai[k] = fmaf(v, e[2*k+1], ai[k]);
        }
    }
    __shared__ float red[20][128][2];   // 20 KB
    if (yq == 1) {
        #pragma unroll
        for (int k = 0; k < 20; k++) { red[k][c][0] = ar[k]; red[k][c][1] = ai[k]; }
    }
    __syncthreads();
    if (yq == 0) {
        float2* Gp = G + ((size_t)(b*256 + x))*20*128;
        #pragma unroll
        for (int k = 0; k < 20; k++)
            Gp[k*128 + c] = make_float2(ar[k] + red[k][c][0], ai[k] + red[k][c][1]);
    }
}

// ---------------- K3: x-DFT  G -> ftT[ic][b][j*20+ky] ----------------
__global__ __launch_bounds__(512) void k_xdft(const float2* __restrict__ G,
        const float* __restrict__ Ex, float2* __restrict__ ftT) {
    // grid 160 = ch(2) x jq(2) x ky(20) x b(2) ; block 512 = xq(8) x cl(64)
    int t = blockIdx.x;
    int ch = t & 1, jq = (t >> 1) & 1, ky = (t >> 2) % 20, b = t / 80;
    int cl = threadIdx.x & 63;
    int xq = __builtin_amdgcn_readfirstlane((int)(threadIdx.x >> 6));  // 0..7
    int c = ch*64 + cl;
    int j0 = jq * 20;
    float ar[20], ai[20];
    #pragma unroll
    for (int k = 0; k < 20; k++) { ar[k] = 0.f; ai[k] = 0.f; }
    for (int i = 0; i < 32; i++) {
        int x = xq*32 + i;
        float2 g = G[(((size_t)(b*256 + x))*20 + ky)*128 + c];
        const float* e = Ex + (size_t)x*80 + j0*2;
        #pragma unroll
        for (int k = 0; k < 20; k++) {
            float er = e[2*k], ei = e[2*k+1];
            ar[k] = fmaf(g.x, er, fmaf(-g.y, ei, ar[k]));
            ai[k] = fmaf(g.x, ei, fmaf( g.y, er, ai[k]));
        }
    }
    __shared__ float red[4][20][64][2];  // 40 KB
    if (xq >= 4) {
        int s = xq - 4;
        #pragma unroll
        for (int k = 0; k < 20; k++) { red[s][k][cl][0] = ar[k]; red[s][k][cl][1] = ai[k]; }
    }
    __syncthreads();
    if (xq < 4) {
        #pragma unroll
        for (int k = 0; k < 20; k++) { ar[k] += red[xq][k][cl][0]; ai[k] += red[xq][k][cl][1]; }
    }
    __syncthreads();
    if (xq == 2 || xq == 3) {
        int s = xq - 2;
        #pragma unroll
        for (int k = 0; k < 20; k++) { red[s][k][cl][0] = ar[k]; red[s][k][cl][1] = ai[k]; }
    }
    __syncthreads();
    if (xq < 2) {
        #pragma unroll
        for (int k = 0; k < 20; k++) { ar[k] += red[xq][k][cl][0]; ai[k] += red[xq][k][cl][1]; }
    }
    __syncthreads();
    if (xq == 1) {
        #pragma unroll
        for (int k = 0; k < 20; k++) { red[0][k][cl][0] = ar[k]; red[0][k][cl][1] = ai[k]; }
    }
    __syncthreads();
    if (xq == 0) {
        #pragma unroll
        for (int k = 0; k < 20; k++) {
            float rr = ar[k] + red[0][k][cl][0];
            float ii = ai[k] + red[0][k][cl][1];
            ftT[((size_t)c*2 + b)*800 + (size_t)(j0 + k)*20 + ky] = make_float2(rr, ii);
        }
    }
}

// ---------------- K4: mode mixing (HBM-heavy einsum, ic-splittable) ----
__global__ __launch_bounds__(448) void k_modemix(const float2* __restrict__ w1,
        const float2* __restrict__ w2, const float2* __restrict__ ftT,
        float2* __restrict__ outp, int ic_per) {
    int bid = blockIdx.x & 255;
    int icq = blockIdx.x >> 8;             // 0 when unsplit
    int oc = bid >> 1;
    int mh = bid & 1;
    int tid = threadIdx.x;
    if (tid >= 400) return;
    int wsel = tid / 200;
    int m = mh*200 + (tid % 200);
    int jk = wsel*400 + m;
    const float2* wb = wsel ? w2 : w1;
    int ic0 = icq * ic_per;
    float ar0=0.f, ai0=0.f, ar1=0.f, ai1=0.f;
    #pragma unroll 4
    for (int i = 0; i < ic_per; i++) {
        int ic = ic0 + i;
        float2 wv = wb[((size_t)(ic*128 + oc))*400 + m];
        float2 f0 = ftT[(size_t)ic*1600 + jk];
        float2 f1 = ftT[(size_t)ic*1600 + 800 + jk];
        ar0 = fmaf(f0.x, wv.x, fmaf(-f0.y, wv.y, ar0));
        ai0 = fmaf(f0.x, wv.y, fmaf( f0.y, wv.x, ai0));
        ar1 = fmaf(f1.x, wv.x, fmaf(-f1.y, wv.y, ar1));
        ai1 = fmaf(f1.x, wv.y, fmaf( f1.y, wv.x, ai1));
    }
    float2* o = outp + (size_t)icq * 204800;
    o[(size_t)jk*128 + oc]         = make_float2(ar0, ai0);
    o[(size_t)(800 + jk)*128 + oc] = make_float2(ar1, ai1);
}

// reduce 8 partials -> oft
__global__ __launch_bounds__(512) void k_modered(const float2* __restrict__ part,
        float2* __restrict__ oft) {
    int i = blockIdx.x * 512 + threadIdx.x;
    if (i >= 204800) return;
    float2 s = part[i];
    #pragma unroll
    for (int q = 1; q < 8; q++) {
        float2 p = part[(size_t)q*204800 + i];
        s.x += p.x; s.y += p.y;
    }
    oft[i] = s;
}

// ---------------- K5: x-IDFT  oft -> T[b][x][ky][oc] (into G buffer) ---
__global__ __launch_bounds__(256) void k_xidft(const float2* __restrict__ oft,
        const float* __restrict__ Exi, float2* __restrict__ T) {
    // grid 256 = b(2) x xq(128) ; block 256 = xs(2) x oc(128)
    int b = blockIdx.x >> 7, xq = blockIdx.x & 127;
    int oc = threadIdx.x & 127;
    int xs = __builtin_amdgcn_readfirstlane((int)(threadIdx.x >> 7));
    int x = xq*2 + xs;
    float ar[20], ai[20];
    #pragma unroll
    for (int k = 0; k < 20; k++) { ar[k] = 0.f; ai[k] = 0.f; }
    const float2* ob = oft + (size_t)b*800*128;
    for (int j = 0; j < 40; j++) {
        float er = Exi[(size_t)x*80 + 2*j], ei = Exi[(size_t)x*80 + 2*j + 1];
        #pragma unroll
        for (int k = 0; k < 20; k++) {
            float2 o = ob[(size_t)(j*20 + k)*128 + oc];
            ar[k] = fmaf(o.x, er, fmaf(-o.y, ei, ar[k]));
            ai[k] = fmaf(o.x, ei, fmaf( o.y, er, ai[k]));
        }
    }
    float2* Tp = T + ((size_t)(b*256 + x))*20*128;
    #pragma unroll
    for (int k = 0; k < 20; k++) Tp[k*128 + oc] = make_float2(ar[k], ai[k]);
}

// ---------------- K6: y-IDFT + pointwise linear + bias + gelu ----------
__global__ __launch_bounds__(256) void k_spec_lin(const float* __restrict__ H,
        const float2* __restrict__ T, const float* __restrict__ wwT,
        const float* __restrict__ wb, float* __restrict__ Hout, int do_gelu) {
    // grid 2048 = ((b*256)+x)*4 + yg ; block 256 = ys(8) x ocg(32)
    int yg = blockIdx.x & 3;
    int x  = (blockIdx.x >> 2) & 255;
    int b  = blockIdx.x >> 10;
    int tid = threadIdx.x;
    int ocg = tid & 31;
    int ys  = tid >> 5;                 // 0..7
    __shared__ float  Hl[64][128];      // 32 KB
    __shared__ float2 Tl[128][22];      // 22.5 KB (padded: 4*44 mod 32 = 16 -> free)
    __shared__ float2 trig[20][64];     // 10 KB
    int y0 = yg*64;
    const float* Hbase = H + (((size_t)(b*256 + x))*256 + y0)*128;
    #pragma unroll
    for (int it = 0; it < 8; it++) {
        int i = tid + it*256;           // < 2048 float4s
        int pi = i >> 5, c4 = (i & 31)*4;
        *(float4*)&Hl[pi][c4] = *(const float4*)&Hbase[(size_t)pi*128 + c4];
    }
    const float2* Tp = T + ((size_t)(b*256 + x))*20*128;
    for (int i = tid; i < 2560; i += 256) Tl[i & 127][i >> 7] = Tp[i];
    for (int i = tid; i < 1280; i += 256) {
        int ky = i >> 6, yl = i & 63;
        int t = (ky * (y0 + yl)) & 255;
        float th = t * (6.2831853071795864769f/256.0f);
        float f = (ky == 0 ? 1.0f : 2.0f) * (1.0f/65536.0f);
        trig[ky][yl] = make_float2(f*cosf(th), f*sinf(th));
    }
    __syncthreads();
    int oc0 = ocg*4;
    float acc[4][8];
    #pragma unroll
    for (int q = 0; q < 4; q++)
        #pragma unroll
        for (int yy = 0; yy < 8; yy++) acc[q][yy] = 0.f;
    // pointwise linear (4-ic chunks, b128 LDS reads)
    for (int icc = 0; icc < 32; icc++) {
        float4 hv[8];
        #pragma unroll
        for (int p = 0; p < 8; p++) hv[p] = *(float4*)&Hl[ys*8 + p][icc*4];
        float4 wA = *(const float4*)&wwT[(size_t)(icc*4+0)*128 + oc0];
        float4 wB = *(const float4*)&wwT[(size_t)(icc*4+1)*128 + oc0];
        float4 wC = *(const float4*)&wwT[(size_t)(icc*4+2)*128 + oc0];
        float4 wD = *(const float4*)&wwT[(size_t)(icc*4+3)*128 + oc0];
        #pragma unroll
        for (int p = 0; p < 8; p++) {
            float4 h4 = hv[p];
            acc[0][p] = fmaf(h4.x, wA.x, fmaf(h4.y, wB.x, fmaf(h4.z, wC.x, fmaf(h4.w, wD.x, acc[0][p]))));
            acc[1][p] = fmaf(h4.x, wA.y, fmaf(h4.y, wB.y, fmaf(h4.z, wC.y, fmaf(h4.w, wD.y, acc[1][p]))));
            acc[2][p] = fmaf(h4.x, wA.z, fmaf(h4.y, wB.z, fmaf(h4.z, wC.z, fmaf(h4.w, wD.z, acc[2][p]))));
            acc[3][p] = fmaf(h4.x, wA.w, fmaf(h4.y, wB.w, fmaf(h4.z, wC.w, fmaf(h4.w, wD.w, acc[3][p]))));
        }
    }
    // spectral part: acc += f(ky)/65536 * (Tr cos - Ti sin)
    #pragma unroll
    for (int ky = 0; ky < 20; ky++) {
        float2 t0 = Tl[oc0+0][ky], t1 = Tl[oc0+1][ky];
        float2 t2 = Tl[oc0+2][ky], t3 = Tl[oc0+3][ky];
        #pragma unroll
        for (int yy = 0; yy < 8; yy++) {
            float2 cs = trig[ky][ys*8+yy];
            acc[0][yy] = fmaf(t0.x, cs.x, fmaf(-t0.y, cs.y, acc[0][yy]));
            acc[1][yy] = fmaf(t1.x, cs.x, fmaf(-t1.y, cs.y, acc[1][yy]));
            acc[2][yy] = fmaf(t2.x, cs.x, fmaf(-t2.y, cs.y, acc[2][yy]));
            acc[3][yy] = fmaf(t3.x, cs.x, fmaf(-t3.y, cs.y, acc[3][yy]));
        }
    }
    float4 bb = *(const float4*)&wb[oc0];
    #pragma unroll
    for (int yy = 0; yy < 8; yy++) {
        float4 o;
        o.x = acc[0][yy] + bb.x; o.y = acc[1][yy] + bb.y;
        o.z = acc[2][yy] + bb.z; o.w = acc[3][yy] + bb.w;
        if (do_gelu) { o.x = gelu_f(o.x); o.y = gelu_f(o.y); o.z = gelu_f(o.z); o.w = gelu_f(o.w); }
        *(float4*)&Hout[(((size_t)(b*256 + x))*256 + y0 + ys*8 + yy)*128 + oc0] = o;
    }
}

// ---------------- K7: crop + fc1 + gelu + heads (fused via LDS) --------
__global__ __launch_bounds__(256) void k_head(const float* __restrict__ H,
        const float* __restrict__ fc1_w, const float* __restrict__ fc1_b,
        const float* __restrict__ h1w, const float* __restrict__ h1b,
        const float* __restrict__ h2w, const float* __restrict__ h2b,
        float* __restrict__ out) {
    int tid = threadIdx.x;
    int p0 = blockIdx.x * 64;              // 1800 blocks, 115200 pixels
    __shared__ float hl[64][128];          // 32 KB
    __shared__ float tl[128][65];          // 33.3 KB (pitch 65: reads broadcast)
    #pragma unroll
    for (int it = 0; it < 8; it++) {
        int i = tid + it*256;              // < 2048 float4s
        int pi = i >> 5, c4 = (i & 31)*4;
        int p = p0 + pi;
        int b = p / 57600, r = p % 57600;
        int xx = r / 240, yy = r % 240;
        *(float4*)&hl[pi][c4] = *(const float4*)&H[(((size_t)(b*256 + xx))*256 + yy)*128 + c4];
    }
    __syncthreads();
    {   // fc1: thread = (ocg 32, pxg 8) -> 4 oc x 8 px
        int ocg = tid & 31, pxg = tid >> 5;
        int oc0 = ocg*4, px0 = pxg*8;
        float acc[4][8];
        #pragma unroll
        for (int q = 0; q < 4; q++)
            #pragma unroll
            for (int p = 0; p < 8; p++) acc[q][p] = 0.f;
        for (int icc = 0; icc < 32; icc++) {
            float4 hv[8];
            #pragma unroll
            for (int p = 0; p < 8; p++) hv[p] = *(float4*)&hl[px0 + p][icc*4];
            float4 wA = *(const float4*)&fc1_w[(size_t)(icc*4+0)*128 + oc0];
            float4 wB = *(const float4*)&fc1_w[(size_t)(icc*4+1)*128 + oc0];
            float4 wC = *(const float4*)&fc1_w[(size_t)(icc*4+2)*128 + oc0];
            float4 wD = *(const float4*)&fc1_w[(size_t)(icc*4+3)*128 + oc0];
            #pragma unroll
            for (int p = 0; p < 8; p++) {
                float4 h4 = hv[p];
                acc[0][p] = fmaf(h4.x, wA.x, fmaf(h4.y, wB.x, fmaf(h4.z, wC.x, fmaf(h4.w, wD.x, acc[0][p]))));
                acc[1][p] = fmaf(h4.x, wA.y, fmaf(h4.y, wB.y, fmaf(h4.z, wC.y, fmaf(h4.w, wD.y, acc[1][p]))));
                acc[2][p] = fmaf(h4.x, wA.z, fmaf(h4.y, wB.z, fmaf(h4.z, wC.z, fmaf(h4.w, wD.z, acc[2][p]))));
                acc[3][p] = fmaf(h4.x, wA.w, fmaf(h4.y, wB.w, fmaf(h4.z, wC.w, fmaf(h4.w, wD.w, acc[3][p]))));
            }
        }
        float4 bb = *(const float4*)&fc1_b[oc0];
        float bq[4] = {bb.x, bb.y, bb.z, bb.w};
        #pragma unroll
        for (int q = 0; q < 4; q++)
            #pragma unroll
            for (int p = 0; p < 8; p++)
                tl[oc0 + q][px0 + p] = gelu_f(acc[q][p] + bq[q]);
    }
    __syncthreads();
    // heads: thread = (k 4, pxg 4, dg 16) -> 4 d x 16 px; reduce over dg
    {
        int k = tid >> 6, dg = tid & 15, pxg = (tid >> 4) & 3;
        int d0 = dg*4, px0 = pxg*16;
        float acc2[4][16];
        #pragma unroll
        for (int q = 0; q < 4; q++)
            #pragma unroll
            for (int i = 0; i < 16; i++) acc2[q][i] = 0.f;
        const float* wp = h1w + (size_t)k*8192 + d0;
        for (int c = 0; c < 128; c++) {
            float4 w = *(const float4*)&wp[(size_t)c*64];
            #pragma unroll
            for (int i = 0; i < 16; i++) {
                float v = tl[c][px0 + i];
                acc2[0][i] = fmaf(v, w.x, acc2[0][i]);
                acc2[1][i] = fmaf(v, w.y, acc2[1][i]);
                acc2[2][i] = fmaf(v, w.z, acc2[2][i]);
                acc2[3][i] = fmaf(v, w.w, acc2[3][i]);
            }
        }
        float4 b1 = *(const float4*)&h1b[k*64 + d0];
        float4 w2 = *(const float4*)&h2w[k*64 + d0];
        float ob = h2b[k];
        #pragma unroll
        for (int i = 0; i < 16; i++) {
            float u = gelu_f(acc2[0][i] + b1.x) * w2.x
                    + gelu_f(acc2[1][i] + b1.y) * w2.y
                    + gelu_f(acc2[2][i] + b1.z) * w2.z
                    + gelu_f(acc2[3][i] + b1.w) * w2.w;
            u += __shfl_down(u, 8);
            u += __shfl_down(u, 4);
            u += __shfl_down(u, 2);
            u += __shfl_down(u, 1);
            if (dg == 0) out[(size_t)k*115200 + p0 + px0 + i] = u + ob;
        }
    }
}

// ---------------- launcher ----------------
extern "C" void kernel_launch(void* const* d_in, const int* in_sizes, int n_in,
                              void* d_out, int out_size, void* d_ws, size_t ws_size,
                              hipStream_t stream) {
    const float* x       = (const float*)d_in[0];
    const float* fc0_w   = (const float*)d_in[1];
    const float* fc0_b   = (const float*)d_in[2];
    const float* spec_w1 = (const float*)d_in[3];
    const float* spec_w2 = (const float*)d_in[4];
    const float* w_w     = (const float*)d_in[5];
    const float* w_b     = (const float*)d_in[6];
    const float* fc1_w   = (const float*)d_in[7];
    const float* fc1_b   = (const float*)d_in[8];
    const float* head1_w = (const float*)d_in[9];
    const float* head1_b = (const float*)d_in[10];
    const float* head2_w = (const float*)d_in[11];
    const float* head2_b = (const float*)d_in[12];
    float* ws = (float*)d_ws;
    float* out = (float*)d_out;

    int split = ws_size >= (size_t)(O_PART + SZ_PART) * 4 ? 1 : 0;

    k_prep<<<420, 256, 0, stream>>>(w_w, ws);
    k_fc0<<<16384, 256, 0, stream>>>(x, fc0_w, fc0_b, (float4*)(ws + O_HA));

    float* cur = ws + O_HA;
    float* nxt = ws + O_HB;
    float2* G    = (float2*)(ws + O_G);
    float2* ftT  = (float2*)(ws + O_FTT);
    float2* oft  = (float2*)(ws + O_OFT);
    float2* part = (float2*)(ws + O_PART);

    for (int l = 0; l < 5; l++) {
        k_ydft<<<512, 256, 0, stream>>>(cur, ws + O_EY, G);
        k_xdft<<<160, 512, 0, stream>>>(G, ws + O_EX, ftT);
        const float2* w1l = (const float2*)(spec_w1 + (size_t)l*13107200);
        const float2* w2l = (const float2*)(spec_w2 + (size_t)l*13107200);
        if (split) {
            k_modemix<<<2048, 448, 0, stream>>>(w1l, w2l, ftT, part, 16);
            k_modered<<<400, 512, 0, stream>>>(part, oft);
        } else {
            k_modemix<<<256, 448, 0, stream>>>(w1l, w2l, ftT, oft, 128);
        }
        k_xidft<<<256, 256, 0, stream>>>(oft, ws + O_EXI, G);   // T into G
        k_spec_lin<<<2048, 256, 0, stream>>>(cur, G, ws + O_WWT + (size_t)l*16384,
                                             w_b + l*128, nxt, (l < 4) ? 1 : 0);
        float* t = cur; cur = nxt; nxt = t;
    }
    k_head<<<1800, 256, 0, stream>>>(cur, fc1_w, fc1_b, head1_w, head1_b,
                                     head2_w, head2_b, out);
}

// Round 3
// 1958.897 us; speedup vs baseline: 1.1664x; 1.0658x over previous
//
#include <hip/hip_runtime.h>
#include <math.h>

// ---------------- problem constants ----------------
// B=2, S=240, WIDTH=128, M=20, PAD=16 -> padded spatial 256x256
// modes: kx in {0..19} (w1) and {236..255} (w2) -> j=0..39 ; ky in {0..19}

// ---------------- ws layout (float offsets) ----------------
#define SZ_H   (2ull*256*256*128)          // 8,388,608 floats
#define O_HA   0ull
#define O_HB   (O_HA + SZ_H)
#define O_G    (O_HB + SZ_H)               // float2[2*256*20*128]
#define SZ_G   (2ull*256*20*128*2)
#define O_FTT  (O_G + SZ_G)                // float2[128*2*800]
#define SZ_FT  (2ull*40*20*128*2)
#define O_OFT  (O_FTT + SZ_FT)
#define O_EY   (O_OFT + SZ_FT)             // float2[256*20]
#define SZ_EY  (256ull*20*2)
#define O_EX   (O_EY + SZ_EY)              // float2[256*40]
#define SZ_EX  (256ull*40*2)
#define O_EXI  (O_EX + SZ_EX)
#define O_WWT  (O_EXI + SZ_EX)             // 5*128*128 transposed w_w
#define SZ_WWT 81920ull
#define O_PART (O_WWT + SZ_WWT)            // 8 x 204800 float2 partials
#define SZ_PART (8ull*204800*2)
// fc1 output (14,745,600 floats) = [O_HA..O_HA+8,388,608) ++ [O_G..O_G+6,356,992)
#define FC1_B_NEED (O_G + 6356992ull)

static __device__ __forceinline__ float gelu_f(float v) {
    return 0.5f * v * (1.0f + erff(v * 0.70710678118654752f));
}

// ---------------- K0: tables + w_w transpose ----------------
__global__ void k_prep(const float* __restrict__ w_w, float* __restrict__ ws) {
    int i = blockIdx.x * 256 + threadIdx.x;
    const float STEP = 6.2831853071795864769f / 256.0f;
    if (i < 5120) {                       // Ey[y][ky] = exp(-2pi i ky y/256)
        int ky = i % 20, y = i / 20;
        int t = (ky * y) & 255;
        float th = t * STEP;
        ws[O_EY + 2*(size_t)i]     = cosf(th);
        ws[O_EY + 2*(size_t)i + 1] = -sinf(th);
    } else if (i < 15360) {               // Ex[x][j] = exp(-2pi i kx x/256)
        int m = i - 5120; int j = m % 40, x = m / 40;
        int kx = (j < 20) ? j : (216 + j);
        int t = (kx * x) & 255;
        float th = t * STEP;
        ws[O_EX + 2*(size_t)m]     = cosf(th);
        ws[O_EX + 2*(size_t)m + 1] = -sinf(th);
    } else if (i < 25600) {               // Exi[x][j] = exp(+2pi i kx x/256)
        int m = i - 15360; int j = m % 40, x = m / 40;
        int kx = (j < 20) ? j : (216 + j);
        int t = (kx * x) & 255;
        float th = t * STEP;
        ws[O_EXI + 2*(size_t)m]     = cosf(th);
        ws[O_EXI + 2*(size_t)m + 1] = sinf(th);
    } else {                              // wwT[l][ic][oc] = w_w[l][oc][ic]
        int m = i - 25600;
        if (m < 81920) {
            int l = m >> 14, r = m & 16383;
            int ic = r >> 7, oc = r & 127;
            ws[O_WWT + m] = w_w[(size_t)l*16384 + oc*128 + ic];
        }
    }
}

// ---------------- K1: fc0 + grid concat + zero-pad (float4) -----------
__global__ __launch_bounds__(256) void k_fc0(const float* __restrict__ xin,
        const float* __restrict__ w, const float* __restrict__ bv,
        float4* __restrict__ H4) {
    size_t e = (size_t)blockIdx.x * 256 + threadIdx.x;   // < 4,194,304
    int c4 = (int)(e & 31) * 4;
    int y = (int)((e >> 5) & 255);
    int x = (int)((e >> 13) & 255);
    int b = (int)(e >> 21);
    float4 h = make_float4(0.f, 0.f, 0.f, 0.f);
    if (x < 240 && y < 240) {
        const float* xp = xin + (((size_t)(b*240 + x))*240 + y)*3;
        float x0 = xp[0], x1 = xp[1], x2 = xp[2];
        float gx = x*(1.0f/239.0f), gy = y*(1.0f/239.0f);
        float4 w0 = *(const float4*)&w[c4];
        float4 w1 = *(const float4*)&w[128 + c4];
        float4 w2 = *(const float4*)&w[256 + c4];
        float4 w3 = *(const float4*)&w[384 + c4];
        float4 w4 = *(const float4*)&w[512 + c4];
        float4 bb = *(const float4*)&bv[c4];
        h.x = bb.x + x0*w0.x + x1*w1.x + x2*w2.x + gx*w3.x + gy*w4.x;
        h.y = bb.y + x0*w0.y + x1*w1.y + x2*w2.y + gx*w3.y + gy*w4.y;
        h.z = bb.z + x0*w0.z + x1*w1.z + x2*w2.z + gx*w3.z + gy*w4.z;
        h.w = bb.w + x0*w0.w + x1*w1.w + x2*w2.w + gx*w3.w + gy*w4.w;
    }
    H4[e] = h;
}

// ---------------- K2: y-DFT  H -> G[b][x][ky][c] ----------------
__global__ __launch_bounds__(256) void k_ydft(const float* __restrict__ H,
        const float* __restrict__ Ey, float2* __restrict__ G) {
    int b = blockIdx.x >> 8, x = blockIdx.x & 255;
    int c = threadIdx.x & 127;
    int yq = __builtin_amdgcn_readfirstlane((int)(threadIdx.x >> 7));  // 0,1
    const float* Hrow = H + ((size_t)(b*256 + x)) * 256 * 128;
    float ar[20], ai[20];
    #pragma unroll
    for (int k = 0; k < 20; k++) { ar[k] = 0.f; ai[k] = 0.f; }
    for (int i = 0; i < 128; i++) {
        int y = yq*128 + i;
        float v = Hrow[(size_t)y*128 + c];
        const float* e = Ey + (size_t)y*40;
        #pragma unroll
        for (int k = 0; k < 20; k++) {
            ar[k] = fmaf(v, e[2*k],   ar[k]);
            ai[k] = fmaf(v, e[2*k+1], ai[k]);
        }
    }
    __shared__ float red[20][128][2];   // 20 KB
    if (yq == 1) {
        #pragma unroll
        for (int k = 0; k < 20; k++) { red[k][c][0] = ar[k]; red[k][c][1] = ai[k]; }
    }
    __syncthreads();
    if (yq == 0) {
        float2* Gp = G + ((size_t)(b*256 + x))*20*128;
        #pragma unroll
        for (int k = 0; k < 20; k++)
            Gp[k*128 + c] = make_float2(ar[k] + red[k][c][0], ai[k] + red[k][c][1]);
    }
}

// ---------------- K3: x-DFT  G -> ftT[ic][b][j*20+ky] ----------------
__global__ __launch_bounds__(512) void k_xdft(const float2* __restrict__ G,
        const float* __restrict__ Ex, float2* __restrict__ ftT) {
    // grid 160 = ch(2) x jq(2) x ky(20) x b(2) ; block 512 = xq(8) x cl(64)
    int t = blockIdx.x;
    int ch = t & 1, jq = (t >> 1) & 1, ky = (t >> 2) % 20, b = t / 80;
    int cl = threadIdx.x & 63;
    int xq = __builtin_amdgcn_readfirstlane((int)(threadIdx.x >> 6));  // 0..7
    int c = ch*64 + cl;
    int j0 = jq * 20;
    float ar[20], ai[20];
    #pragma unroll
    for (int k = 0; k < 20; k++) { ar[k] = 0.f; ai[k] = 0.f; }
    for (int i = 0; i < 32; i++) {
        int x = xq*32 + i;
        float2 g = G[(((size_t)(b*256 + x))*20 + ky)*128 + c];
        const float* e = Ex + (size_t)x*80 + j0*2;
        #pragma unroll
        for (int k = 0; k < 20; k++) {
            float er = e[2*k], ei = e[2*k+1];
            ar[k] = fmaf(g.x, er, fmaf(-g.y, ei, ar[k]));
            ai[k] = fmaf(g.x, ei, fmaf( g.y, er, ai[k]));
        }
    }
    __shared__ float red[4][20][64][2];  // 40 KB
    if (xq >= 4) {
        int s = xq - 4;
        #pragma unroll
        for (int k = 0; k < 20; k++) { red[s][k][cl][0] = ar[k]; red[s][k][cl][1] = ai[k]; }
    }
    __syncthreads();
    if (xq < 4) {
        #pragma unroll
        for (int k = 0; k < 20; k++) { ar[k] += red[xq][k][cl][0]; ai[k] += red[xq][k][cl][1]; }
    }
    __syncthreads();
    if (xq == 2 || xq == 3) {
        int s = xq - 2;
        #pragma unroll
        for (int k = 0; k < 20; k++) { red[s][k][cl][0] = ar[k]; red[s][k][cl][1] = ai[k]; }
    }
    __syncthreads();
    if (xq < 2) {
        #pragma unroll
        for (int k = 0; k < 20; k++) { ar[k] += red[xq][k][cl][0]; ai[k] += red[xq][k][cl][1]; }
    }
    __syncthreads();
    if (xq == 1) {
        #pragma unroll
        for (int k = 0; k < 20; k++) { red[0][k][cl][0] = ar[k]; red[0][k][cl][1] = ai[k]; }
    }
    __syncthreads();
    if (xq == 0) {
        #pragma unroll
        for (int k = 0; k < 20; k++) {
            float rr = ar[k] + red[0][k][cl][0];
            float ii = ai[k] + red[0][k][cl][1];
            ftT[((size_t)c*2 + b)*800 + (size_t)(j0 + k)*20 + ky] = make_float2(rr, ii);
        }
    }
}

// ---------------- K4: mode mixing (HBM-heavy einsum, ic-splittable) ----
__global__ __launch_bounds__(448) void k_modemix(const float2* __restrict__ w1,
        const float2* __restrict__ w2, const float2* __restrict__ ftT,
        float2* __restrict__ outp, int ic_per) {
    int bid = blockIdx.x & 255;
    int icq = blockIdx.x >> 8;             // 0 when unsplit
    int oc = bid >> 1;
    int mh = bid & 1;
    int tid = threadIdx.x;
    if (tid >= 400) return;
    int wsel = tid / 200;
    int m = mh*200 + (tid % 200);
    int jk = wsel*400 + m;
    const float2* wb = wsel ? w2 : w1;
    int ic0 = icq * ic_per;
    float ar0=0.f, ai0=0.f, ar1=0.f, ai1=0.f;
    #pragma unroll 4
    for (int i = 0; i < ic_per; i++) {
        int ic = ic0 + i;
        float2 wv = wb[((size_t)(ic*128 + oc))*400 + m];
        float2 f0 = ftT[(size_t)ic*1600 + jk];
        float2 f1 = ftT[(size_t)ic*1600 + 800 + jk];
        ar0 = fmaf(f0.x, wv.x, fmaf(-f0.y, wv.y, ar0));
        ai0 = fmaf(f0.x, wv.y, fmaf( f0.y, wv.x, ai0));
        ar1 = fmaf(f1.x, wv.x, fmaf(-f1.y, wv.y, ar1));
        ai1 = fmaf(f1.x, wv.y, fmaf( f1.y, wv.x, ai1));
    }
    float2* o = outp + (size_t)icq * 204800;
    o[(size_t)jk*128 + oc]         = make_float2(ar0, ai0);
    o[(size_t)(800 + jk)*128 + oc] = make_float2(ar1, ai1);
}

// reduce 8 partials -> oft
__global__ __launch_bounds__(512) void k_modered(const float2* __restrict__ part,
        float2* __restrict__ oft) {
    int i = blockIdx.x * 512 + threadIdx.x;
    if (i >= 204800) return;
    float2 s = part[i];
    #pragma unroll
    for (int q = 1; q < 8; q++) {
        float2 p = part[(size_t)q*204800 + i];
        s.x += p.x; s.y += p.y;
    }
    oft[i] = s;
}

// ---------------- K5: x-IDFT  oft -> T[b][x][ky][oc] (into G buffer) ---
__global__ __launch_bounds__(256) void k_xidft(const float2* __restrict__ oft,
        const float* __restrict__ Exi, float2* __restrict__ T) {
    // grid 256 = b(2) x xq(128) ; block 256 = xs(2) x oc(128)
    int b = blockIdx.x >> 7, xq = blockIdx.x & 127;
    int oc = threadIdx.x & 127;
    int xs = __builtin_amdgcn_readfirstlane((int)(threadIdx.x >> 7));
    int x = xq*2 + xs;
    float ar[20], ai[20];
    #pragma unroll
    for (int k = 0; k < 20; k++) { ar[k] = 0.f; ai[k] = 0.f; }
    const float2* ob = oft + (size_t)b*800*128;
    for (int j = 0; j < 40; j++) {
        float er = Exi[(size_t)x*80 + 2*j], ei = Exi[(size_t)x*80 + 2*j + 1];
        #pragma unroll
        for (int k = 0; k < 20; k++) {
            float2 o = ob[(size_t)(j*20 + k)*128 + oc];
            ar[k] = fmaf(o.x, er, fmaf(-o.y, ei, ar[k]));
            ai[k] = fmaf(o.x, ei, fmaf( o.y, er, ai[k]));
        }
    }
    float2* Tp = T + ((size_t)(b*256 + x))*20*128;
    #pragma unroll
    for (int k = 0; k < 20; k++) Tp[k*128 + oc] = make_float2(ar[k], ai[k]);
}

// -------- K6: y-IDFT + pointwise linear + bias + gelu (scalar-operand) --
__global__ __launch_bounds__(256) void k_spec_lin(const float* __restrict__ H,
        const float2* __restrict__ T, const float* __restrict__ wwT,
        const float* __restrict__ wb, float* __restrict__ Hout, int do_gelu) {
    // grid 2048 = ((b*256)+x)*4 + yg ; block 256 = 4 waves (32 oc each) x 64 y-lanes
    int yg = blockIdx.x & 3;
    int x  = (blockIdx.x >> 2) & 255;
    int b  = blockIdx.x >> 10;
    int tid = threadIdx.x;
    int lane = tid & 63;
    int wv = __builtin_amdgcn_readfirstlane(tid >> 6);   // 0..3
    int oc0 = wv * 32;
    int y0 = yg * 64;
    __shared__ float hl[64][129];     // 33 KB, pitch 129 -> lane-stride-1 reads free
    const float* Hbase = H + (((size_t)(b*256 + x))*256 + y0)*128;
    #pragma unroll
    for (int it = 0; it < 8; it++) {
        int i = tid + it*256;                // 2048 float4
        int pi = i >> 5, c4 = (i & 31)*4;
        float4 v = *(const float4*)&Hbase[(size_t)pi*128 + c4];
        hl[pi][c4] = v.x; hl[pi][c4+1] = v.y; hl[pi][c4+2] = v.z; hl[pi][c4+3] = v.w;
    }
    // per-lane trig (f(ky)/65536 folded in)
    float csr[20], csi[20];
    {
        int y = y0 + lane;
        #pragma unroll
        for (int k = 0; k < 20; k++) {
            int t = (k * y) & 255;
            float th = t * (6.2831853071795864769f/256.0f);
            float f = (k == 0 ? 1.0f : 2.0f) * (1.0f/65536.0f);
            csr[k] = f * __cosf(th);
            csi[k] = f * __sinf(th);
        }
    }
    __syncthreads();
    float acc[32];
    #pragma unroll
    for (int o = 0; o < 32; o++) acc[o] = 0.f;
    // pointwise linear: weights via wave-uniform scalar loads
    for (int ic = 0; ic < 128; ic++) {
        float t = hl[lane][ic];
        const float* wr = &wwT[(size_t)ic*128 + oc0];
        #pragma unroll
        for (int o4 = 0; o4 < 8; o4++) {
            float4 w = *(const float4*)&wr[o4*4];
            acc[o4*4]   = fmaf(t, w.x, acc[o4*4]);
            acc[o4*4+1] = fmaf(t, w.y, acc[o4*4+1]);
            acc[o4*4+2] = fmaf(t, w.z, acc[o4*4+2]);
            acc[o4*4+3] = fmaf(t, w.w, acc[o4*4+3]);
        }
    }
    // spectral: T values wave-uniform (s_load), trig lane-varying
    const float2* Tp = T + ((size_t)(b*256 + x))*20*128 + oc0;
    for (int k = 0; k < 20; k++) {
        const float2* tr = Tp + (size_t)k*128;
        float cr = csr[k], ci = csi[k];
        #pragma unroll
        for (int o = 0; o < 32; o++) {
            float2 tv = tr[o];
            acc[o] = fmaf(tv.x, cr, fmaf(-tv.y, ci, acc[o]));
        }
    }
    __syncthreads();            // all hl reads complete
    const float* bp = &wb[oc0];
    #pragma unroll
    for (int o = 0; o < 32; o++) {
        float v = acc[o] + bp[o];
        if (do_gelu) v = gelu_f(v);
        hl[lane][oc0 + o] = v;  // transpose through LDS (stride-1 lanes: free)
    }
    __syncthreads();
    float* Obase = Hout + (((size_t)(b*256 + x))*256 + y0)*128;
    #pragma unroll
    for (int it = 0; it < 32; it++) {
        int i = tid + it*256;   // 8192 floats
        int pi = i >> 7, c = i & 127;
        Obase[(size_t)pi*128 + c] = hl[pi][c];
    }
}

// ---------------- K7a: crop + fc1 + gelu -> staged fc1out --------------
__global__ __launch_bounds__(128) void k_fc1(const float* __restrict__ H,
        const float* __restrict__ fc1_w, const float* __restrict__ fc1_b,
        float* __restrict__ outA, float* __restrict__ outB) {
    int tid = threadIdx.x;
    int lane = tid & 63;
    int wv = __builtin_amdgcn_readfirstlane(tid >> 6);  // 0..1
    int p0 = blockIdx.x * 64;              // 1800 blocks
    __shared__ float hl[64][129];
    #pragma unroll
    for (int it = 0; it < 16; it++) {
        int i = tid + it*128;              // 2048 float4
        int pi = i >> 5, c4 = (i & 31)*4;
        int p = p0 + pi;
        int bb = p / 57600, r = p % 57600;
        int xx = r / 240, yy = r % 240;
        float4 v = *(const float4*)&H[(((size_t)(bb*256 + xx))*256 + yy)*128 + c4];
        hl[pi][c4] = v.x; hl[pi][c4+1] = v.y; hl[pi][c4+2] = v.z; hl[pi][c4+3] = v.w;
    }
    __syncthreads();
    int oc0 = wv*64;
    float acc[64];
    #pragma unroll
    for (int o = 0; o < 64; o++) acc[o] = 0.f;
    for (int ic = 0; ic < 128; ic++) {
        float t = hl[lane][ic];
        const float* wr = &fc1_w[(size_t)ic*128 + oc0];
        #pragma unroll
        for (int o4 = 0; o4 < 16; o4++) {
            float4 w = *(const float4*)&wr[o4*4];
            acc[o4*4]   = fmaf(t, w.x, acc[o4*4]);
            acc[o4*4+1] = fmaf(t, w.y, acc[o4*4+1]);
            acc[o4*4+2] = fmaf(t, w.z, acc[o4*4+2]);
            acc[o4*4+3] = fmaf(t, w.w, acc[o4*4+3]);
        }
    }
    __syncthreads();
    const float* bp = &fc1_b[oc0];
    #pragma unroll
    for (int o = 0; o < 64; o++) hl[lane][oc0 + o] = gelu_f(acc[o] + bp[o]);
    __syncthreads();
    float* outp = (p0 < 65536) ? (outA + (size_t)p0*128)
                               : (outB + ((size_t)(p0 - 65536))*128);
    #pragma unroll
    for (int it = 0; it < 64; it++) {
        int i = tid + it*128;              // 8192 floats
        int pi = i >> 7, c = i & 127;
        outp[(size_t)pi*128 + c] = hl[pi][c];
    }
}

// ---------------- K7b: heads (h1 gelu + h2 dot), lane = pixel ----------
__global__ __launch_bounds__(256) void k_heads(const float* __restrict__ inA,
        const float* __restrict__ inB, const float* __restrict__ h1w,
        const float* __restrict__ h1b, const float* __restrict__ h2w,
        const float* __restrict__ h2b, float* __restrict__ out) {
    int tid = threadIdx.x;
    int lane = tid & 63;
    int k = __builtin_amdgcn_readfirstlane(tid >> 6);   // head index = wave
    int p0 = blockIdx.x * 64;              // 1800 blocks
    __shared__ float tl[128][65];          // 33.3 KB
    const float* inp = (p0 < 65536) ? (inA + (size_t)p0*128)
                                    : (inB + ((size_t)(p0 - 65536))*128);
    #pragma unroll
    for (int it = 0; it < 8; it++) {
        int i = tid + it*256;              // 2048 float4
        int pi = i >> 5, c4 = (i & 31)*4;
        float4 v = *(const float4*)&inp[(size_t)pi*128 + c4];
        tl[c4][pi] = v.x; tl[c4+1][pi] = v.y; tl[c4+2][pi] = v.z; tl[c4+3][pi] = v.w;
    }
    __syncthreads();
    float acc[64];
    #pragma unroll
    for (int d = 0; d < 64; d++) acc[d] = 0.f;
    const float* wk = h1w + (size_t)k*8192;
    for (int c = 0; c < 128; c++) {
        float t = tl[c][lane];
        const float* wr = &wk[c*64];
        #pragma unroll
        for (int d4 = 0; d4 < 16; d4++) {
            float4 w = *(const float4*)&wr[d4*4];
            acc[d4*4]   = fmaf(t, w.x, acc[d4*4]);
            acc[d4*4+1] = fmaf(t, w.y, acc[d4*4+1]);
            acc[d4*4+2] = fmaf(t, w.z, acc[d4*4+2]);
            acc[d4*4+3] = fmaf(t, w.w, acc[d4*4+3]);
        }
    }
    const float* b1 = &h1b[k*64];
    const float* w2 = &h2w[k*64];
    float res = 0.f;
    #pragma unroll
    for (int d = 0; d < 64; d++)
        res += gelu_f(acc[d] + b1[d]) * w2[d];
    out[(size_t)k*115200 + p0 + lane] = res + h2b[k];
}

// ---------------- fused fallback (small ws): old k_head ----------------
__global__ __launch_bounds__(256) void k_head(const float* __restrict__ H,
        const float* __restrict__ fc1_w, const float* __restrict__ fc1_b,
        const float* __restrict__ h1w, const float* __restrict__ h1b,
        const float* __restrict__ h2w, const float* __restrict__ h2b,
        float* __restrict__ out) {
    int tid = threadIdx.x;
    int p0 = blockIdx.x * 64;
    __shared__ float hl[64][128];
    __shared__ float tl[128][65];
    #pragma unroll
    for (int it = 0; it < 8; it++) {
        int i = tid + it*256;
        int pi = i >> 5, c4 = (i & 31)*4;
        int p = p0 + pi;
        int b = p / 57600, r = p % 57600;
        int xx = r / 240, yy = r % 240;
        *(float4*)&hl[pi][c4] = *(const float4*)&H[(((size_t)(b*256 + xx))*256 + yy)*128 + c4];
    }
    __syncthreads();
    {
        int ocg = tid & 31, pxg = tid >> 5;
        int oc0 = ocg*4, px0 = pxg*8;
        float acc[4][8];
        #pragma unroll
        for (int q = 0; q < 4; q++)
            #pragma unroll
            for (int p = 0; p < 8; p++) acc[q][p] = 0.f;
        for (int icc = 0; icc < 32; icc++) {
            float4 hv[8];
            #pragma unroll
            for (int p = 0; p < 8; p++) hv[p] = *(float4*)&hl[px0 + p][icc*4];
            float4 wA = *(const float4*)&fc1_w[(size_t)(icc*4+0)*128 + oc0];
            float4 wB = *(const float4*)&fc1_w[(size_t)(icc*4+1)*128 + oc0];
            float4 wC = *(const float4*)&fc1_w[(size_t)(icc*4+2)*128 + oc0];
            float4 wD = *(const float4*)&fc1_w[(size_t)(icc*4+3)*128 + oc0];
            #pragma unroll
            for (int p = 0; p < 8; p++) {
                float4 h4 = hv[p];
                acc[0][p] = fmaf(h4.x, wA.x, fmaf(h4.y, wB.x, fmaf(h4.z, wC.x, fmaf(h4.w, wD.x, acc[0][p]))));
                acc[1][p] = fmaf(h4.x, wA.y, fmaf(h4.y, wB.y, fmaf(h4.z, wC.y, fmaf(h4.w, wD.y, acc[1][p]))));
                acc[2][p] = fmaf(h4.x, wA.z, fmaf(h4.y, wB.z, fmaf(h4.z, wC.z, fmaf(h4.w, wD.z, acc[2][p]))));
                acc[3][p] = fmaf(h4.x, wA.w, fmaf(h4.y, wB.w, fmaf(h4.z, wC.w, fmaf(h4.w, wD.w, acc[3][p]))));
            }
        }
        float4 bb = *(const float4*)&fc1_b[oc0];
        float bq[4] = {bb.x, bb.y, bb.z, bb.w};
        #pragma unroll
        for (int q = 0; q < 4; q++)
            #pragma unroll
            for (int p = 0; p < 8; p++)
                tl[oc0 + q][px0 + p] = gelu_f(acc[q][p] + bq[q]);
    }
    __syncthreads();
    {
        int k = tid >> 6, dg = tid & 15, pxg = (tid >> 4) & 3;
        int d0 = dg*4, px0 = pxg*16;
        float acc2[4][16];
        #pragma unroll
        for (int q = 0; q < 4; q++)
            #pragma unroll
            for (int i = 0; i < 16; i++) acc2[q][i] = 0.f;
        const float* wp = h1w + (size_t)k*8192 + d0;
        for (int c = 0; c < 128; c++) {
            float4 w = *(const float4*)&wp[(size_t)c*64];
            #pragma unroll
            for (int i = 0; i < 16; i++) {
                float v = tl[c][px0 + i];
                acc2[0][i] = fmaf(v, w.x, acc2[0][i]);
                acc2[1][i] = fmaf(v, w.y, acc2[1][i]);
                acc2[2][i] = fmaf(v, w.z, acc2[2][i]);
                acc2[3][i] = fmaf(v, w.w, acc2[3][i]);
            }
        }
        float4 b1 = *(const float4*)&h1b[k*64 + d0];
        float4 w2 = *(const float4*)&h2w[k*64 + d0];
        float ob = h2b[k];
        #pragma unroll
        for (int i = 0; i < 16; i++) {
            float u = gelu_f(acc2[0][i] + b1.x) * w2.x
                    + gelu_f(acc2[1][i] + b1.y) * w2.y
                    + gelu_f(acc2[2][i] + b1.z) * w2.z
                    + gelu_f(acc2[3][i] + b1.w) * w2.w;
            u += __shfl_down(u, 8);
            u += __shfl_down(u, 4);
            u += __shfl_down(u, 2);
            u += __shfl_down(u, 1);
            if (dg == 0) out[(size_t)k*115200 + p0 + px0 + i] = u + ob;
        }
    }
}

// ---------------- launcher ----------------
extern "C" void kernel_launch(void* const* d_in, const int* in_sizes, int n_in,
                              void* d_out, int out_size, void* d_ws, size_t ws_size,
                              hipStream_t stream) {
    const float* x       = (const float*)d_in[0];
    const float* fc0_w   = (const float*)d_in[1];
    const float* fc0_b   = (const float*)d_in[2];
    const float* spec_w1 = (const float*)d_in[3];
    const float* spec_w2 = (const float*)d_in[4];
    const float* w_w     = (const float*)d_in[5];
    const float* w_b     = (const float*)d_in[6];
    const float* fc1_w   = (const float*)d_in[7];
    const float* fc1_b   = (const float*)d_in[8];
    const float* head1_w = (const float*)d_in[9];
    const float* head1_b = (const float*)d_in[10];
    const float* head2_w = (const float*)d_in[11];
    const float* head2_b = (const float*)d_in[12];
    float* ws = (float*)d_ws;
    float* out = (float*)d_out;

    int split      = ws_size >= (size_t)(O_PART + SZ_PART) * 4 ? 1 : 0;
    int head_split = ws_size >= (size_t)FC1_B_NEED * 4 ? 1 : 0;

    k_prep<<<420, 256, 0, stream>>>(w_w, ws);
    k_fc0<<<16384, 256, 0, stream>>>(x, fc0_w, fc0_b, (float4*)(ws + O_HA));

    float* cur = ws + O_HA;
    float* nxt = ws + O_HB;
    float2* G    = (float2*)(ws + O_G);
    float2* ftT  = (float2*)(ws + O_FTT);
    float2* oft  = (float2*)(ws + O_OFT);
    float2* part = (float2*)(ws + O_PART);

    for (int l = 0; l < 5; l++) {
        k_ydft<<<512, 256, 0, stream>>>(cur, ws + O_EY, G);
        k_xdft<<<160, 512, 0, stream>>>(G, ws + O_EX, ftT);
        const float2* w1l = (const float2*)(spec_w1 + (size_t)l*13107200);
        const float2* w2l = (const float2*)(spec_w2 + (size_t)l*13107200);
        if (split) {
            k_modemix<<<2048, 448, 0, stream>>>(w1l, w2l, ftT, part, 16);
            k_modered<<<400, 512, 0, stream>>>(part, oft);
        } else {
            k_modemix<<<256, 448, 0, stream>>>(w1l, w2l, ftT, oft, 128);
        }
        k_xidft<<<256, 256, 0, stream>>>(oft, ws + O_EXI, G);   // T into G
        k_spec_lin<<<2048, 256, 0, stream>>>(cur, G, ws + O_WWT + (size_t)l*16384,
                                             w_b + l*128, nxt, (l < 4) ? 1 : 0);
        float* t = cur; cur = nxt; nxt = t;
    }
    // after 5 layers: cur == ws+O_HB ; ws+O_HA and everything from O_G on are free
    if (head_split) {
        float* fA = ws + O_HA;     // pixels [0, 65536)
        float* fB = ws + O_G;      // pixels [65536, 115200)
        k_fc1<<<1800, 128, 0, stream>>>(cur, fc1_w, fc1_b, fA, fB);
        k_heads<<<1800, 256, 0, stream>>>(fA, fB, head1_w, head1_b,
                                          head2_w, head2_b, out);
    } else {
        k_head<<<1800, 256, 0, stream>>>(cur, fc1_w, fc1_b, head1_w, head1_b,
                                         head2_w, head2_b, out);
    }
}